// Round 1
// baseline (347.136 us; speedup 1.0000x reference)
//
#include <hip/hip_runtime.h>
#include <hip/hip_bf16.h>

#define N_NODES 5000
#define N_EDGES 80000
#define BATCH   32
#define FDIM    64
#define BF      (BATCH * FDIM)   // 2048

// ---- workspace layout (bytes) ----
// zero region [0, 49152): deg, fill, pooled
#define OFF_DEG      0          // int[5000]
#define OFF_FILL     20480      // int[5000]
#define OFF_POOLED   40960      // float[2048]
#define ZERO_BYTES   49152
#define OFF_FLAG     49152      // int[1]  (written unconditionally)
#define OFF_DINV     49408      // float[5000]
#define OFF_ROWPTR   69632      // int[5001]
#define OFF_EDGES    90112      // int[160000]  (src then dst, normalized int32)
#define OFF_COL      730112     // int[80000]
#define OFF_VAL      1050112    // float[80000]
#define OFF_XT       1370112    // float[5000*32]
#define OFF_S        2010112    // float[5000*32]
#define OFF_T        2650112    // float[5000*32*64]  ends at ~43.6 MB

__device__ inline void fma4(float4& a, float v, const float4& u) {
    a.x = fmaf(v, u.x, a.x); a.y = fmaf(v, u.y, a.y);
    a.z = fmaf(v, u.z, a.z); a.w = fmaf(v, u.w, a.w);
}

// Detect whether edge_index buffer is int64 (odd 32-bit words all zero) or int32.
__global__ void k_detect(const unsigned int* raw, int* flag) {
    unsigned int hi = raw[2 * threadIdx.x + 1];
    unsigned long long b = __ballot(hi == 0u);
    if (threadIdx.x == 0) flag[0] = (b == ~0ull) ? 1 : 0;
}

// Normalize edges to int32 [2*N_EDGES]
__global__ void k_convert(const int* raw, const int* flag, int* edges) {
    int i = blockIdx.x * 256 + threadIdx.x;
    if (i >= 2 * N_EDGES) return;
    edges[i] = flag[0] ? raw[2 * i] : raw[i];
}

__global__ void k_degree(const int* edges, int* deg) {
    int e = blockIdx.x * 256 + threadIdx.x;
    if (e < N_EDGES) atomicAdd(&deg[edges[N_EDGES + e]], 1);
}

__global__ void k_dinv(const int* deg, float* dinv) {
    int n = blockIdx.x * 256 + threadIdx.x;
    if (n < N_NODES) dinv[n] = 1.0f / sqrtf((float)deg[n] + 1.0f);  // +1 self-loop
}

// Single-block exclusive scan of deg[5000] -> row_ptr[5001]
__global__ void k_scan(const int* deg, int* row_ptr) {
    __shared__ int part[1024];
    int tid = threadIdx.x;
    int base = tid * 5;
    int local[5];
    int sum = 0;
    for (int i = 0; i < 5; i++) {
        int idx = base + i;
        int v = (idx < N_NODES) ? deg[idx] : 0;
        local[i] = sum;
        sum += v;
    }
    part[tid] = sum;
    __syncthreads();
    for (int off = 1; off < 1024; off <<= 1) {
        int v = (tid >= off) ? part[tid - off] : 0;
        __syncthreads();
        part[tid] += v;
        __syncthreads();
    }
    int prefix = (tid > 0) ? part[tid - 1] : 0;
    for (int i = 0; i < 5; i++) {
        int idx = base + i;
        if (idx < N_NODES) row_ptr[idx] = prefix + local[i];
    }
    if (tid == 1023) row_ptr[N_NODES] = part[1023];
}

__global__ void k_fill(const int* edges, const int* row_ptr, int* fill,
                       const float* dinv, int* col, float* val) {
    int e = blockIdx.x * 256 + threadIdx.x;
    if (e >= N_EDGES) return;
    int s = edges[e];
    int d = edges[N_EDGES + e];
    int pos = atomicAdd(&fill[d], 1);
    int idx = row_ptr[d] + pos;
    col[idx] = s;
    val[idx] = dinv[s] * dinv[d];
}

__global__ void k_transpose(const float* x, float* xT) {
    int i = blockIdx.x * 256 + threadIdx.x;
    if (i >= BATCH * N_NODES) return;
    int b = i / N_NODES, n = i % N_NODES;
    xT[n * BATCH + b] = x[i];
}

// s = Âx : width-32 SpMM. 8 nodes per 256-thread block, 32 lanes (=batch) per node.
__global__ __launch_bounds__(256) void k_spmm1(const float* xT, const int* row_ptr,
                                               const int* col, const float* val,
                                               const float* dinv, float* s_out) {
    int g = threadIdx.x >> 5;
    int lane = threadIdx.x & 31;
    int n = blockIdx.x * 8 + g;
    if (n >= N_NODES) return;
    float dv = dinv[n];
    float acc = dv * dv * xT[n * BATCH + lane];
    int beg = row_ptr[n], end = row_ptr[n + 1];
    for (int i = beg; i < end; ++i)
        acc += val[i] * xT[col[i] * BATCH + lane];
    s_out[n * BATCH + lane] = acc;
}

// t[row, f] = sum_k relu(s[row]*W1[k]+b1[k]) * W2[k][f]  (h1 never materialized)
__global__ __launch_bounds__(256) void k_h1gemm(const float* s_in, const float* W1,
                                                const float* b1, const float* W2,
                                                float* t) {
    int lane = threadIdx.x & 63;
    int wave = (blockIdx.x * 256 + threadIdx.x) >> 6;  // global wave id
    float w1l = W1[lane];
    float b1l = b1[lane];
    float w2c[64];
#pragma unroll
    for (int k = 0; k < 64; k++) w2c[k] = W2[k * 64 + lane];
    int row0 = wave * 16;
    for (int r = 0; r < 16; r++) {
        int row = row0 + r;
        float sval = s_in[row];
        float h1 = fmaxf(fmaf(sval, w1l, b1l), 0.0f);
        float acc = 0.0f;
#pragma unroll
        for (int k = 0; k < 64; k++)
            acc = fmaf(__shfl(h1, k), w2c[k], acc);
        t[row * 64 + lane] = acc;
    }
}

// Layer-2 aggregation over t (width 2048) fused with bias+ReLU+transpose into d_out.
__global__ __launch_bounds__(256) void k_spmm2(const float* t, const int* row_ptr,
                                               const int* col, const float* val,
                                               const float* dinv, const float* b2,
                                               float* out) {
    int n = blockIdx.x;
    int idx0 = threadIdx.x * 8;             // 0..2040
    const float4* t4 = (const float4*)t;
    float dv = dinv[n];
    float dv2 = dv * dv;
    int v0 = (n * BF + idx0) >> 2;
    float4 a0 = t4[v0], a1 = t4[v0 + 1];
    float4 acc0, acc1;
    acc0.x = dv2 * a0.x; acc0.y = dv2 * a0.y; acc0.z = dv2 * a0.z; acc0.w = dv2 * a0.w;
    acc1.x = dv2 * a1.x; acc1.y = dv2 * a1.y; acc1.z = dv2 * a1.z; acc1.w = dv2 * a1.w;
    int beg = row_ptr[n], end = row_ptr[n + 1];
    for (int i = beg; i < end; ++i) {
        int src = col[i];
        float v = val[i];
        int q = (src * BF + idx0) >> 2;
        float4 u0 = t4[q], u1 = t4[q + 1];
        fma4(acc0, v, u0);
        fma4(acc1, v, u1);
    }
    int f0 = idx0 & 63;
    int b = idx0 >> 6;
    float4 r0, r1;
    r0.x = fmaxf(acc0.x + b2[f0 + 0], 0.f);
    r0.y = fmaxf(acc0.y + b2[f0 + 1], 0.f);
    r0.z = fmaxf(acc0.z + b2[f0 + 2], 0.f);
    r0.w = fmaxf(acc0.w + b2[f0 + 3], 0.f);
    r1.x = fmaxf(acc1.x + b2[f0 + 4], 0.f);
    r1.y = fmaxf(acc1.y + b2[f0 + 5], 0.f);
    r1.z = fmaxf(acc1.z + b2[f0 + 6], 0.f);
    r1.w = fmaxf(acc1.w + b2[f0 + 7], 0.f);
    float* o = out + 2 * BF + (size_t)b * (N_NODES * FDIM) + n * FDIM + f0;
    ((float4*)o)[0] = r0;
    ((float4*)o)[1] = r1;
}

// pooled[b,f] = sum_n gene[b,n,f] (mean applied in head). 32 b x 20 chunks of 250.
__global__ void k_pooled(const float* out, float* pooled) {
    int bid = blockIdx.x;
    int b = bid / 20, chunk = bid % 20;
    int f = threadIdx.x;
    const float* g = out + 2 * BF + (size_t)b * (N_NODES * FDIM) + chunk * 250 * FDIM + f;
    float acc = 0.f;
    for (int n = 0; n < 250; n++) acc += g[n * FDIM];
    atomicAdd(&pooled[b * FDIM + f], acc);
}

__global__ void k_head(const float* pooled, const float* Wmu, const float* bmu,
                       const float* Wlv, const float* blv, float* out) {
    int id = blockIdx.x * 256 + threadIdx.x;
    if (id >= BF) return;
    int b = id >> 6, f = id & 63;
    const float sc = 1.0f / 5000.0f;
    float mu = bmu[f], lv = blv[f];
    for (int k = 0; k < 64; k++) {
        float p = pooled[b * 64 + k] * sc;
        mu = fmaf(p, Wmu[k * 64 + f], mu);
        lv = fmaf(p, Wlv[k * 64 + f], lv);
    }
    out[id] = mu;
    out[BF + id] = lv;
}

extern "C" void kernel_launch(void* const* d_in, const int* in_sizes, int n_in,
                              void* d_out, int out_size, void* d_ws, size_t ws_size,
                              hipStream_t stream) {
    const float* x   = (const float*)d_in[0];
    const int*   era = (const int*)d_in[1];
    const float* W1  = (const float*)d_in[2];
    const float* b1  = (const float*)d_in[3];
    const float* W2  = (const float*)d_in[4];
    const float* b2  = (const float*)d_in[5];
    const float* Wmu = (const float*)d_in[6];
    const float* bmu = (const float*)d_in[7];
    const float* Wlv = (const float*)d_in[8];
    const float* blv = (const float*)d_in[9];
    float* out = (float*)d_out;
    char*  ws  = (char*)d_ws;

    int*   deg    = (int*)(ws + OFF_DEG);
    int*   fill   = (int*)(ws + OFF_FILL);
    float* pooled = (float*)(ws + OFF_POOLED);
    int*   flag   = (int*)(ws + OFF_FLAG);
    float* dinv   = (float*)(ws + OFF_DINV);
    int*   rowp   = (int*)(ws + OFF_ROWPTR);
    int*   edges  = (int*)(ws + OFF_EDGES);
    int*   col    = (int*)(ws + OFF_COL);
    float* val    = (float*)(ws + OFF_VAL);
    float* xT     = (float*)(ws + OFF_XT);
    float* s      = (float*)(ws + OFF_S);
    float* t      = (float*)(ws + OFF_T);

    hipMemsetAsync(ws, 0, ZERO_BYTES, stream);
    k_detect<<<1, 64, 0, stream>>>((const unsigned int*)era, flag);
    k_convert<<<625, 256, 0, stream>>>(era, flag, edges);
    k_degree<<<313, 256, 0, stream>>>(edges, deg);
    k_transpose<<<625, 256, 0, stream>>>(x, xT);
    k_dinv<<<20, 256, 0, stream>>>(deg, dinv);
    k_scan<<<1, 1024, 0, stream>>>(deg, rowp);
    k_fill<<<313, 256, 0, stream>>>(edges, rowp, fill, dinv, col, val);
    k_spmm1<<<625, 256, 0, stream>>>(xT, rowp, col, val, dinv, s);
    k_h1gemm<<<2500, 256, 0, stream>>>(s, W1, b1, W2, t);
    k_spmm2<<<5000, 256, 0, stream>>>(t, rowp, col, val, dinv, b2, out);
    k_pooled<<<640, 64, 0, stream>>>(out, pooled);
    k_head<<<8, 256, 0, stream>>>(pooled, Wmu, bmu, Wlv, blv, out);
}

// Round 2
// 245.972 us; speedup vs baseline: 1.4113x; 1.4113x over previous
//
#include <hip/hip_runtime.h>
#include <hip/hip_bf16.h>

#define N_NODES 5000
#define N_EDGES 80000
#define BATCH   32
#define FDIM    64
#define BF      (BATCH * FDIM)   // 2048

// ---- workspace layout (bytes) ----
#define OFF_DEG      0          // int[5000]
#define OFF_FILL     20480      // int[5000]
#define OFF_POOLED   40960      // float[2048]
#define ZERO_BYTES   49152
#define OFF_FLAG     49152      // int[1]
#define OFF_DINV     49408      // float[5000]
#define OFF_ROWPTR   69632      // int[5001]
#define OFF_EDGES    90112      // int[160000]
#define OFF_COL      730112     // int[80000]
#define OFF_VAL      1050112    // float[80000]
#define OFF_XT       1370112    // float[5000*32]
#define OFF_S        2010112    // float[5000*32]
#define OFF_T        2650112    // float[5000*32*64]

typedef __attribute__((ext_vector_type(8))) short short8;
typedef __attribute__((ext_vector_type(4))) float f32x4;

__device__ inline short f2bf(float f) {           // RTNE f32 -> bf16 bits
    unsigned u = __builtin_bit_cast(unsigned, f);
    unsigned r = (u + 0x7fffu + ((u >> 16) & 1u)) >> 16;
    return (short)r;
}
__device__ inline float bf2f(short h) {
    unsigned u = ((unsigned)(unsigned short)h) << 16;
    return __builtin_bit_cast(float, u);
}

__device__ inline void fma4(float4& a, float v, const float4& u) {
    a.x = fmaf(v, u.x, a.x); a.y = fmaf(v, u.y, a.y);
    a.z = fmaf(v, u.z, a.z); a.w = fmaf(v, u.w, a.w);
}

__global__ void k_detect(const unsigned int* raw, int* flag) {
    unsigned int hi = raw[2 * threadIdx.x + 1];
    unsigned long long b = __ballot(hi == 0u);
    if (threadIdx.x == 0) flag[0] = (b == ~0ull) ? 1 : 0;
}

__global__ void k_convert(const int* raw, const int* flag, int* edges) {
    int i = blockIdx.x * 256 + threadIdx.x;
    if (i >= 2 * N_EDGES) return;
    edges[i] = flag[0] ? raw[2 * i] : raw[i];
}

__global__ void k_degree(const int* edges, int* deg) {
    int e = blockIdx.x * 256 + threadIdx.x;
    if (e < N_EDGES) atomicAdd(&deg[edges[N_EDGES + e]], 1);
}

__global__ void k_dinv(const int* deg, float* dinv) {
    int n = blockIdx.x * 256 + threadIdx.x;
    if (n < N_NODES) dinv[n] = 1.0f / sqrtf((float)deg[n] + 1.0f);
}

__global__ void k_scan(const int* deg, int* row_ptr) {
    __shared__ int part[1024];
    int tid = threadIdx.x;
    int base = tid * 5;
    int local[5];
    int sum = 0;
    for (int i = 0; i < 5; i++) {
        int idx = base + i;
        int v = (idx < N_NODES) ? deg[idx] : 0;
        local[i] = sum;
        sum += v;
    }
    part[tid] = sum;
    __syncthreads();
    for (int off = 1; off < 1024; off <<= 1) {
        int v = (tid >= off) ? part[tid - off] : 0;
        __syncthreads();
        part[tid] += v;
        __syncthreads();
    }
    int prefix = (tid > 0) ? part[tid - 1] : 0;
    for (int i = 0; i < 5; i++) {
        int idx = base + i;
        if (idx < N_NODES) row_ptr[idx] = prefix + local[i];
    }
    if (tid == 1023) row_ptr[N_NODES] = part[1023];
}

__global__ void k_fill(const int* edges, const int* row_ptr, int* fill,
                       const float* dinv, int* col, float* val) {
    int e = blockIdx.x * 256 + threadIdx.x;
    if (e >= N_EDGES) return;
    int s = edges[e];
    int d = edges[N_EDGES + e];
    int pos = atomicAdd(&fill[d], 1);
    int idx = row_ptr[d] + pos;
    col[idx] = s;
    val[idx] = dinv[s] * dinv[d];
}

__global__ void k_transpose(const float* x, float* xT) {
    int i = blockIdx.x * 256 + threadIdx.x;
    if (i >= BATCH * N_NODES) return;
    int b = i / N_NODES, n = i % N_NODES;
    xT[n * BATCH + b] = x[i];
}

__global__ __launch_bounds__(256) void k_spmm1(const float* __restrict__ xT,
                                               const int* __restrict__ row_ptr,
                                               const int* __restrict__ col,
                                               const float* __restrict__ val,
                                               const float* __restrict__ dinv,
                                               float* __restrict__ s_out) {
    int g = threadIdx.x >> 5;
    int lane = threadIdx.x & 31;
    int n = blockIdx.x * 8 + g;
    if (n >= N_NODES) return;
    float dv = dinv[n];
    float acc = dv * dv * xT[n * BATCH + lane];
    int beg = row_ptr[n], end = row_ptr[n + 1];
    int i = beg;
    for (; i + 2 <= end; i += 2) {
        float a0 = val[i]     * xT[col[i]     * BATCH + lane];
        float a1 = val[i + 1] * xT[col[i + 1] * BATCH + lane];
        acc += a0 + a1;
    }
    if (i < end) acc += val[i] * xT[col[i] * BATCH + lane];
    s_out[n * BATCH + lane] = acc;
}

// t = relu(s (outer) W1 + b1) @ W2 on matrix cores, bf16 hi/lo split (3 MFMAs/term).
// Wave handles 5 M-tiles of 16 rows; W2 frags loaded+split once per wave.
__global__ __launch_bounds__(256) void k_tgemm(const float* __restrict__ s_in,
                                               const float* __restrict__ W1,
                                               const float* __restrict__ b1,
                                               const float* __restrict__ W2,
                                               float* __restrict__ t) {
    int lane = threadIdx.x & 63;
    int c = lane & 15;          // A-row / D-col / B-col
    int g = lane >> 4;          // k-octet group
    int wave = (blockIdx.x * 256 + threadIdx.x) >> 6;   // 0..1999

    short8 bh[2][4], bl[2][4];
#pragma unroll
    for (int kt = 0; kt < 2; kt++)
#pragma unroll
        for (int nt = 0; nt < 4; nt++)
#pragma unroll
            for (int j = 0; j < 8; j++) {
                float w = W2[(kt * 32 + g * 8 + j) * 64 + nt * 16 + c];
                short hi = f2bf(w);
                bh[kt][nt][j] = hi;
                bl[kt][nt][j] = f2bf(w - bf2f(hi));
            }
    float w1r[2][8], b1r[2][8];
#pragma unroll
    for (int kt = 0; kt < 2; kt++)
#pragma unroll
        for (int j = 0; j < 8; j++) {
            int k = kt * 32 + g * 8 + j;
            w1r[kt][j] = W1[k];
            b1r[kt][j] = b1[k];
        }

    for (int mt = 0; mt < 5; mt++) {
        int row0 = (wave * 5 + mt) * 16;
        float sv = s_in[row0 + c];
        short8 ah[2], al[2];
#pragma unroll
        for (int kt = 0; kt < 2; kt++)
#pragma unroll
            for (int j = 0; j < 8; j++) {
                float h = fmaxf(fmaf(sv, w1r[kt][j], b1r[kt][j]), 0.0f);
                short hi = f2bf(h);
                ah[kt][j] = hi;
                al[kt][j] = f2bf(h - bf2f(hi));
            }
        f32x4 acc[4];
#pragma unroll
        for (int nt = 0; nt < 4; nt++) acc[nt] = (f32x4){0.f, 0.f, 0.f, 0.f};
#pragma unroll
        for (int nt = 0; nt < 4; nt++)
#pragma unroll
            for (int kt = 0; kt < 2; kt++) {
                acc[nt] = __builtin_amdgcn_mfma_f32_16x16x32_bf16(ah[kt], bh[kt][nt], acc[nt], 0, 0, 0);
                acc[nt] = __builtin_amdgcn_mfma_f32_16x16x32_bf16(ah[kt], bl[kt][nt], acc[nt], 0, 0, 0);
                acc[nt] = __builtin_amdgcn_mfma_f32_16x16x32_bf16(al[kt], bh[kt][nt], acc[nt], 0, 0, 0);
            }
#pragma unroll
        for (int nt = 0; nt < 4; nt++)
#pragma unroll
            for (int r = 0; r < 4; r++)
                t[(size_t)(row0 + g * 4 + r) * 64 + nt * 16 + c] = acc[nt][r];
    }
}

// Layer-2 aggregation fused with bias+ReLU+transpose into d_out. 2-way edge unroll.
__global__ __launch_bounds__(256) void k_spmm2(const float* __restrict__ t,
                                               const int* __restrict__ row_ptr,
                                               const int* __restrict__ col,
                                               const float* __restrict__ val,
                                               const float* __restrict__ dinv,
                                               const float* __restrict__ b2,
                                               float* __restrict__ out) {
    int n = blockIdx.x;
    int idx0 = threadIdx.x * 8;
    const float4* t4 = (const float4*)t;
    float dv = dinv[n];
    float dv2 = dv * dv;
    int v0 = (n * BF + idx0) >> 2;
    float4 a0 = t4[v0], a1 = t4[v0 + 1];
    float4 acc0, acc1;
    acc0.x = dv2 * a0.x; acc0.y = dv2 * a0.y; acc0.z = dv2 * a0.z; acc0.w = dv2 * a0.w;
    acc1.x = dv2 * a1.x; acc1.y = dv2 * a1.y; acc1.z = dv2 * a1.z; acc1.w = dv2 * a1.w;
    int beg = row_ptr[n], end = row_ptr[n + 1];
    int i = beg;
    for (; i + 2 <= end; i += 2) {
        int s0 = col[i], s1 = col[i + 1];
        float w0 = val[i], w1 = val[i + 1];
        int q0 = (s0 * BF + idx0) >> 2;
        int q1 = (s1 * BF + idx0) >> 2;
        float4 u00 = t4[q0], u01 = t4[q0 + 1];
        float4 u10 = t4[q1], u11 = t4[q1 + 1];
        fma4(acc0, w0, u00); fma4(acc1, w0, u01);
        fma4(acc0, w1, u10); fma4(acc1, w1, u11);
    }
    if (i < end) {
        int s0 = col[i];
        float w0 = val[i];
        int q0 = (s0 * BF + idx0) >> 2;
        float4 u00 = t4[q0], u01 = t4[q0 + 1];
        fma4(acc0, w0, u00); fma4(acc1, w0, u01);
    }
    int f0 = idx0 & 63;
    int b = idx0 >> 6;
    float4 r0, r1;
    r0.x = fmaxf(acc0.x + b2[f0 + 0], 0.f);
    r0.y = fmaxf(acc0.y + b2[f0 + 1], 0.f);
    r0.z = fmaxf(acc0.z + b2[f0 + 2], 0.f);
    r0.w = fmaxf(acc0.w + b2[f0 + 3], 0.f);
    r1.x = fmaxf(acc1.x + b2[f0 + 4], 0.f);
    r1.y = fmaxf(acc1.y + b2[f0 + 5], 0.f);
    r1.z = fmaxf(acc1.z + b2[f0 + 6], 0.f);
    r1.w = fmaxf(acc1.w + b2[f0 + 7], 0.f);
    float* o = out + 2 * BF + (size_t)b * (N_NODES * FDIM) + n * FDIM + f0;
    ((float4*)o)[0] = r0;
    ((float4*)o)[1] = r1;
}

__global__ void k_pooled(const float* __restrict__ out, float* __restrict__ pooled) {
    int bid = blockIdx.x;
    int b = bid / 20, chunk = bid % 20;
    int f = threadIdx.x;
    const float* g = out + 2 * BF + (size_t)b * (N_NODES * FDIM) + chunk * 250 * FDIM + f;
    float acc = 0.f;
    for (int n = 0; n < 250; n++) acc += g[n * FDIM];
    atomicAdd(&pooled[b * FDIM + f], acc);
}

__global__ void k_head(const float* __restrict__ pooled, const float* __restrict__ Wmu,
                       const float* __restrict__ bmu, const float* __restrict__ Wlv,
                       const float* __restrict__ blv, float* __restrict__ out) {
    int id = blockIdx.x * 256 + threadIdx.x;
    if (id >= BF) return;
    int b = id >> 6, f = id & 63;
    const float sc = 1.0f / 5000.0f;
    float mu = bmu[f], lv = blv[f];
    for (int k = 0; k < 64; k++) {
        float p = pooled[b * 64 + k] * sc;
        mu = fmaf(p, Wmu[k * 64 + f], mu);
        lv = fmaf(p, Wlv[k * 64 + f], lv);
    }
    out[id] = mu;
    out[BF + id] = lv;
}

extern "C" void kernel_launch(void* const* d_in, const int* in_sizes, int n_in,
                              void* d_out, int out_size, void* d_ws, size_t ws_size,
                              hipStream_t stream) {
    const float* x   = (const float*)d_in[0];
    const int*   era = (const int*)d_in[1];
    const float* W1  = (const float*)d_in[2];
    const float* b1  = (const float*)d_in[3];
    const float* W2  = (const float*)d_in[4];
    const float* b2  = (const float*)d_in[5];
    const float* Wmu = (const float*)d_in[6];
    const float* bmu = (const float*)d_in[7];
    const float* Wlv = (const float*)d_in[8];
    const float* blv = (const float*)d_in[9];
    float* out = (float*)d_out;
    char*  ws  = (char*)d_ws;

    int*   deg    = (int*)(ws + OFF_DEG);
    int*   fill   = (int*)(ws + OFF_FILL);
    float* pooled = (float*)(ws + OFF_POOLED);
    int*   flag   = (int*)(ws + OFF_FLAG);
    float* dinv   = (float*)(ws + OFF_DINV);
    int*   rowp   = (int*)(ws + OFF_ROWPTR);
    int*   edges  = (int*)(ws + OFF_EDGES);
    int*   col    = (int*)(ws + OFF_COL);
    float* val    = (float*)(ws + OFF_VAL);
    float* xT     = (float*)(ws + OFF_XT);
    float* s      = (float*)(ws + OFF_S);
    float* t      = (float*)(ws + OFF_T);

    hipMemsetAsync(ws, 0, ZERO_BYTES, stream);
    k_detect<<<1, 64, 0, stream>>>((const unsigned int*)era, flag);
    k_convert<<<625, 256, 0, stream>>>(era, flag, edges);
    k_degree<<<313, 256, 0, stream>>>(edges, deg);
    k_transpose<<<625, 256, 0, stream>>>(x, xT);
    k_dinv<<<20, 256, 0, stream>>>(deg, dinv);
    k_scan<<<1, 1024, 0, stream>>>(deg, rowp);
    k_fill<<<313, 256, 0, stream>>>(edges, rowp, fill, dinv, col, val);
    k_spmm1<<<625, 256, 0, stream>>>(xT, rowp, col, val, dinv, s);
    k_tgemm<<<500, 256, 0, stream>>>(s, W1, b1, W2, t);
    k_spmm2<<<5000, 256, 0, stream>>>(t, rowp, col, val, dinv, b2, out);
    k_pooled<<<640, 64, 0, stream>>>(out, pooled);
    k_head<<<8, 256, 0, stream>>>(pooled, Wmu, bmu, Wlv, blv, out);
}

// Round 4
// 231.554 us; speedup vs baseline: 1.4992x; 1.0623x over previous
//
#include <hip/hip_runtime.h>
#include <hip/hip_bf16.h>

#define N_NODES 5000
#define N_EDGES 80000
#define BATCH   32
#define FDIM    64
#define BF      (BATCH * FDIM)   // 2048

// ---- workspace layout (bytes) ----
#define OFF_DEG      0          // int[5000]
#define OFF_FILL     20480      // int[5000]
#define OFF_POOLED   40960      // float[2048]
#define ZERO_BYTES   49152
#define OFF_DINV     49408      // float[5000]
#define OFF_ROWPTR   69632      // int[5001]
#define OFF_EDGES    90112      // int[160000]
#define OFF_COL      730112     // int[80000]
#define OFF_VAL      1050112    // float[80000]
#define OFF_XT       1370112    // float[5000*32]
#define OFF_S        2010112    // float[5000*32]

// convert (int64|int32 -> int32) + dst-degree, with inline dtype detection
__global__ void k_edges(const unsigned int* __restrict__ raw,
                        int* __restrict__ edges, int* __restrict__ deg) {
    // every wave probes hi-words of the first 64 entries; int64 edge values
    // (<5000) have hi==0; int32 data there is random values -> not all zero
    unsigned int hi = raw[2 * (threadIdx.x & 63) + 1];
    bool is64 = (__ballot(hi == 0u) == ~0ull);
    int i = blockIdx.x * 256 + threadIdx.x;
    if (i < 2 * N_EDGES) {
        int v = is64 ? (int)raw[2 * i] : (int)raw[i];
        edges[i] = v;
        if (i >= N_EDGES) atomicAdd(&deg[v], 1);
    }
}

// exclusive scan of deg[5000] -> row_ptr[5001], fused dinv = 1/sqrt(deg+1)
__global__ void k_scan(const int* __restrict__ deg, int* __restrict__ row_ptr,
                       float* __restrict__ dinv) {
    __shared__ int part[1024];
    int tid = threadIdx.x;
    int base = tid * 5;
    int local[5];
    int sum = 0;
    for (int i = 0; i < 5; i++) {
        int idx = base + i;
        int v = 0;
        if (idx < N_NODES) {
            v = deg[idx];
            dinv[idx] = 1.0f / sqrtf((float)v + 1.0f);  // +1 self-loop
        }
        local[i] = sum;
        sum += v;
    }
    part[tid] = sum;
    __syncthreads();
    for (int off = 1; off < 1024; off <<= 1) {
        int v = (tid >= off) ? part[tid - off] : 0;
        __syncthreads();
        part[tid] += v;
        __syncthreads();
    }
    int prefix = (tid > 0) ? part[tid - 1] : 0;
    for (int i = 0; i < 5; i++) {
        int idx = base + i;
        if (idx < N_NODES) row_ptr[idx] = prefix + local[i];
    }
    if (tid == 1023) row_ptr[N_NODES] = part[1023];
}

__global__ void k_fill(const int* __restrict__ edges, const int* __restrict__ row_ptr,
                       int* __restrict__ fill, const float* __restrict__ dinv,
                       int* __restrict__ col, float* __restrict__ val) {
    int e = blockIdx.x * 256 + threadIdx.x;
    if (e >= N_EDGES) return;
    int s = edges[e];
    int d = edges[N_EDGES + e];
    int pos = atomicAdd(&fill[d], 1);
    int idx = row_ptr[d] + pos;
    col[idx] = s;
    val[idx] = dinv[s] * dinv[d];
}

__global__ void k_transpose(const float* __restrict__ x, float* __restrict__ xT) {
    int i = blockIdx.x * 256 + threadIdx.x;
    if (i >= BATCH * N_NODES) return;
    int b = i / N_NODES, n = i % N_NODES;
    xT[n * BATCH + b] = x[i];
}

// s = Â x : width-32 SpMM (gathers 128B xT rows, L2-resident)
__global__ __launch_bounds__(256) void k_spmm1(const float* __restrict__ xT,
                                               const int* __restrict__ row_ptr,
                                               const int* __restrict__ col,
                                               const float* __restrict__ val,
                                               const float* __restrict__ dinv,
                                               float* __restrict__ s_out) {
    int g = threadIdx.x >> 5;
    int lane = threadIdx.x & 31;
    int n = blockIdx.x * 8 + g;
    if (n >= N_NODES) return;
    float dv = dinv[n];
    float acc = dv * dv * xT[n * BATCH + lane];
    int beg = row_ptr[n], end = row_ptr[n + 1];
    int i = beg;
    for (; i + 2 <= end; i += 2) {
        float a0 = val[i]     * xT[col[i]     * BATCH + lane];
        float a1 = val[i + 1] * xT[col[i + 1] * BATCH + lane];
        acc += a0 + a1;
    }
    if (i < end) acc += val[i] * xT[col[i] * BATCH + lane];
    s_out[n * BATCH + lane] = acc;
}

// Fused layer-1 recompute + layer-2 aggregation + W2 GEMM + bias + ReLU + transpose.
// Key: agg2 = (Â @ relu(s⊗W1+b1)) @ W2, and relu-row is a function of scalar s[row]
// -> gather 4B/ (edge,batch) instead of 8KB/edge.
// Block = 1 node, 256 threads = (g = tid>>5 in 0..7, b = tid&31).
__global__ __launch_bounds__(256) void k_l2fused(const float* __restrict__ s,
                                                 const int* __restrict__ row_ptr,
                                                 const int* __restrict__ col,
                                                 const float* __restrict__ val,
                                                 const float* __restrict__ dinv,
                                                 const float* __restrict__ W1,
                                                 const float* __restrict__ b1,
                                                 const float* __restrict__ W2,
                                                 const float* __restrict__ b2,
                                                 float* __restrict__ out) {
    __shared__ float lds[FDIM][BATCH];   // [k][b]: writes 2-way (free), reads clean
    int n = blockIdx.x;
    int g = threadIdx.x >> 5, b = threadIdx.x & 31;
    float w1r[8], b1r[8];
#pragma unroll
    for (int j = 0; j < 8; j++) { w1r[j] = W1[g * 8 + j]; b1r[j] = b1[g * 8 + j]; }

    float dv = dinv[n];
    float dv2 = dv * dv;
    float sv = s[n * BATCH + b];
    float acc[8];
#pragma unroll
    for (int j = 0; j < 8; j++)
        acc[j] = dv2 * fmaxf(fmaf(sv, w1r[j], b1r[j]), 0.0f);

    int beg = row_ptr[n], end = row_ptr[n + 1];
    int i = beg;
    for (; i + 2 <= end; i += 2) {
        int s0 = col[i], s1 = col[i + 1];
        float w0 = val[i], w1v = val[i + 1];
        float sn0 = s[s0 * BATCH + b];
        float sn1 = s[s1 * BATCH + b];
#pragma unroll
        for (int j = 0; j < 8; j++)
            acc[j] = fmaf(w0, fmaxf(fmaf(sn0, w1r[j], b1r[j]), 0.0f), acc[j]);
#pragma unroll
        for (int j = 0; j < 8; j++)
            acc[j] = fmaf(w1v, fmaxf(fmaf(sn1, w1r[j], b1r[j]), 0.0f), acc[j]);
    }
    if (i < end) {
        int s0 = col[i];
        float w0 = val[i];
        float sn0 = s[s0 * BATCH + b];
#pragma unroll
        for (int j = 0; j < 8; j++)
            acc[j] = fmaf(w0, fmaxf(fmaf(sn0, w1r[j], b1r[j]), 0.0f), acc[j]);
    }
#pragma unroll
    for (int j = 0; j < 8; j++) lds[g * 8 + j][b] = acc[j];
    __syncthreads();

    // phase 3: out[b, f] = relu(b2[f] + sum_k agg[k,b] * W2[k,f]); thread f-slice g*8..+7
    const float4* W2v = (const float4*)W2;
    float o[8];
#pragma unroll
    for (int j = 0; j < 8; j++) o[j] = b2[g * 8 + j];
#pragma unroll 4
    for (int k = 0; k < 64; k++) {
        float hv = lds[k][b];
        float4 wa = W2v[k * 16 + g * 2];
        float4 wb = W2v[k * 16 + g * 2 + 1];
        o[0] = fmaf(hv, wa.x, o[0]); o[1] = fmaf(hv, wa.y, o[1]);
        o[2] = fmaf(hv, wa.z, o[2]); o[3] = fmaf(hv, wa.w, o[3]);
        o[4] = fmaf(hv, wb.x, o[4]); o[5] = fmaf(hv, wb.y, o[5]);
        o[6] = fmaf(hv, wb.z, o[6]); o[7] = fmaf(hv, wb.w, o[7]);
    }
    float4 r0, r1;
    r0.x = fmaxf(o[0], 0.f); r0.y = fmaxf(o[1], 0.f);
    r0.z = fmaxf(o[2], 0.f); r0.w = fmaxf(o[3], 0.f);
    r1.x = fmaxf(o[4], 0.f); r1.y = fmaxf(o[5], 0.f);
    r1.z = fmaxf(o[6], 0.f); r1.w = fmaxf(o[7], 0.f);
    float* op = out + 2 * BF + (size_t)b * (N_NODES * FDIM) + n * FDIM + g * 8;
    ((float4*)op)[0] = r0;
    ((float4*)op)[1] = r1;
}

// pooled[b,f] += partial sums; 640 blocks x 256 threads (4 row-subgroups of 64 f)
__global__ __launch_bounds__(256) void k_pooled(const float* __restrict__ out,
                                                float* __restrict__ pooled) {
    int bid = blockIdx.x;
    int b = bid / 20, chunk = bid % 20;
    int sub = threadIdx.x >> 6;
    int f = threadIdx.x & 63;
    const float* g = out + 2 * BF + (size_t)b * (N_NODES * FDIM) + (chunk * 250) * FDIM + f;
    int r0 = sub * 63;
    int r1 = r0 + 63; if (r1 > 250) r1 = 250;
    float acc = 0.f;
    for (int r = r0; r < r1; r++) acc += g[r * FDIM];
    atomicAdd(&pooled[b * FDIM + f], acc);
}

__global__ void k_head(const float* __restrict__ pooled, const float* __restrict__ Wmu,
                       const float* __restrict__ bmu, const float* __restrict__ Wlv,
                       const float* __restrict__ blv, float* __restrict__ out) {
    int id = blockIdx.x * 256 + threadIdx.x;
    if (id >= BF) return;
    int b = id >> 6, f = id & 63;
    const float sc = 1.0f / 5000.0f;
    float mu = bmu[f], lv = blv[f];
    for (int k = 0; k < 64; k++) {
        float p = pooled[b * 64 + k] * sc;
        mu = fmaf(p, Wmu[k * 64 + f], mu);
        lv = fmaf(p, Wlv[k * 64 + f], lv);
    }
    out[id] = mu;
    out[BF + id] = lv;
}

extern "C" void kernel_launch(void* const* d_in, const int* in_sizes, int n_in,
                              void* d_out, int out_size, void* d_ws, size_t ws_size,
                              hipStream_t stream) {
    const float* x   = (const float*)d_in[0];
    const int*   era = (const int*)d_in[1];
    const float* W1  = (const float*)d_in[2];
    const float* b1  = (const float*)d_in[3];
    const float* W2  = (const float*)d_in[4];
    const float* b2  = (const float*)d_in[5];
    const float* Wmu = (const float*)d_in[6];
    const float* bmu = (const float*)d_in[7];
    const float* Wlv = (const float*)d_in[8];
    const float* blv = (const float*)d_in[9];
    float* out = (float*)d_out;
    char*  ws  = (char*)d_ws;

    int*   deg    = (int*)(ws + OFF_DEG);
    int*   fill   = (int*)(ws + OFF_FILL);
    float* pooled = (float*)(ws + OFF_POOLED);
    float* dinv   = (float*)(ws + OFF_DINV);
    int*   rowp   = (int*)(ws + OFF_ROWPTR);
    int*   edges  = (int*)(ws + OFF_EDGES);
    int*   col    = (int*)(ws + OFF_COL);
    float* val    = (float*)(ws + OFF_VAL);
    float* xT     = (float*)(ws + OFF_XT);
    float* s      = (float*)(ws + OFF_S);

    hipMemsetAsync(ws, 0, ZERO_BYTES, stream);
    k_edges<<<625, 256, 0, stream>>>((const unsigned int*)era, edges, deg);
    k_transpose<<<625, 256, 0, stream>>>(x, xT);
    k_scan<<<1, 1024, 0, stream>>>(deg, rowp, dinv);
    k_fill<<<313, 256, 0, stream>>>(edges, rowp, fill, dinv, col, val);
    k_spmm1<<<625, 256, 0, stream>>>(xT, rowp, col, val, dinv, s);
    k_l2fused<<<5000, 256, 0, stream>>>(s, rowp, col, val, dinv, W1, b1, W2, b2, out);
    k_pooled<<<640, 256, 0, stream>>>(out, pooled);
    k_head<<<8, 256, 0, stream>>>(pooled, Wmu, bmu, Wlv, blv, out);
}

// Round 5
// 174.083 us; speedup vs baseline: 1.9941x; 1.3301x over previous
//
#include <hip/hip_runtime.h>
#include <hip/hip_bf16.h>

#define N_NODES 5000
#define N_EDGES 80000
#define BATCH   32
#define FDIM    64
#define BF      (BATCH * FDIM)   // 2048

// ---- workspace layout (bytes) ----
#define OFF_DEG      0          // int[5000]
#define OFF_FILL     20480      // int[5000]
#define OFF_POOLED   40960      // float[2048]
#define ZERO_BYTES   49152
#define OFF_DINV     49408      // float[5000]
#define OFF_ROWPTR   69632      // int[5001]
#define OFF_EDGES    90112      // int[160000]
#define OFF_COL      730112     // int[80000]
#define OFF_VAL      1050112    // float[80000]
#define OFF_XT       1370112    // float[5000*32]
#define OFF_S        2010112    // float[5000*32]

// convert (int64|int32 -> int32) + dst-degree, with inline dtype detection
__global__ void k_edges(const unsigned int* __restrict__ raw,
                        int* __restrict__ edges, int* __restrict__ deg) {
    unsigned int hi = raw[2 * (threadIdx.x & 63) + 1];
    bool is64 = (__ballot(hi == 0u) == ~0ull);
    int i = blockIdx.x * 256 + threadIdx.x;
    if (i < 2 * N_EDGES) {
        int v = is64 ? (int)raw[2 * i] : (int)raw[i];
        edges[i] = v;
        if (i >= N_EDGES) atomicAdd(&deg[v], 1);
    }
}

// exclusive scan of deg[5000] -> row_ptr[5001], fused dinv = 1/sqrt(deg+1)
__global__ void k_scan(const int* __restrict__ deg, int* __restrict__ row_ptr,
                       float* __restrict__ dinv) {
    __shared__ int part[1024];
    int tid = threadIdx.x;
    int base = tid * 5;
    int local[5];
    int sum = 0;
    for (int i = 0; i < 5; i++) {
        int idx = base + i;
        int v = 0;
        if (idx < N_NODES) {
            v = deg[idx];
            dinv[idx] = 1.0f / sqrtf((float)v + 1.0f);
        }
        local[i] = sum;
        sum += v;
    }
    part[tid] = sum;
    __syncthreads();
    for (int off = 1; off < 1024; off <<= 1) {
        int v = (tid >= off) ? part[tid - off] : 0;
        __syncthreads();
        part[tid] += v;
        __syncthreads();
    }
    int prefix = (tid > 0) ? part[tid - 1] : 0;
    for (int i = 0; i < 5; i++) {
        int idx = base + i;
        if (idx < N_NODES) row_ptr[idx] = prefix + local[i];
    }
    if (tid == 1023) row_ptr[N_NODES] = part[1023];
}

__global__ void k_fill(const int* __restrict__ edges, const int* __restrict__ row_ptr,
                       int* __restrict__ fill, const float* __restrict__ dinv,
                       int* __restrict__ col, float* __restrict__ val) {
    int e = blockIdx.x * 256 + threadIdx.x;
    if (e >= N_EDGES) return;
    int s = edges[e];
    int d = edges[N_EDGES + e];
    int pos = atomicAdd(&fill[d], 1);
    int idx = row_ptr[d] + pos;
    col[idx] = s;
    val[idx] = dinv[s] * dinv[d];
}

__global__ void k_transpose(const float* __restrict__ x, float* __restrict__ xT) {
    int i = blockIdx.x * 256 + threadIdx.x;
    if (i >= BATCH * N_NODES) return;
    int b = i / N_NODES, n = i % N_NODES;
    xT[n * BATCH + b] = x[i];
}

// s = Â x : width-32 SpMM with 8-deep gather prefetch
__global__ __launch_bounds__(256) void k_spmm1(const float* __restrict__ xT,
                                               const int* __restrict__ row_ptr,
                                               const int* __restrict__ col,
                                               const float* __restrict__ val,
                                               const float* __restrict__ dinv,
                                               float* __restrict__ s_out) {
    int g = threadIdx.x >> 5;
    int lane = threadIdx.x & 31;
    int n = blockIdx.x * 8 + g;
    if (n >= N_NODES) return;
    float dv = dinv[n];
    float acc = dv * dv * xT[n * BATCH + lane];
    int beg = row_ptr[n], end = row_ptr[n + 1];
    for (int i = beg; i < end; i += 8) {
        float pv[8], wv[8];
#pragma unroll
        for (int u = 0; u < 8; u++) {
            int e = i + u;
            int c = (e < end) ? col[e] : n;
            wv[u] = (e < end) ? val[e] : 0.0f;
            pv[u] = xT[c * BATCH + lane];
        }
#pragma unroll
        for (int u = 0; u < 8; u++) acc = fmaf(wv[u], pv[u], acc);
    }
    s_out[n * BATCH + lane] = acc;
}

// Fused layer-1 recompute + layer-2 aggregation + W2 GEMM + bias + ReLU + transpose.
// Per block (node): W2 staged in LDS, 8-deep s-gather prefetch, agg in LDS, GEMM
// from LDS (broadcast reads), scattered 256B/thread-pair writes to out.
__global__ __launch_bounds__(256) void k_l2fused(const float* __restrict__ s,
                                                 const int* __restrict__ row_ptr,
                                                 const int* __restrict__ col,
                                                 const float* __restrict__ val,
                                                 const float* __restrict__ dinv,
                                                 const float* __restrict__ W1,
                                                 const float* __restrict__ b1,
                                                 const float* __restrict__ W2,
                                                 const float* __restrict__ b2,
                                                 float* __restrict__ out) {
    __shared__ float w2s[64 * 64];        // 16 KB, [k][f]
    __shared__ float aggs[FDIM][BATCH];   // 8 KB,  [k][b]
    int n = blockIdx.x;
    int g = threadIdx.x >> 5, b = threadIdx.x & 31;

    // stage W2 -> LDS (1024 float4, 4 per thread)
    const float4* W2v4 = (const float4*)W2;
    float4* w2s4 = (float4*)w2s;
#pragma unroll
    for (int u = 0; u < 4; u++)
        w2s4[u * 256 + threadIdx.x] = W2v4[u * 256 + threadIdx.x];

    float w1r[8], b1r[8];
#pragma unroll
    for (int j = 0; j < 8; j++) { w1r[j] = W1[g * 8 + j]; b1r[j] = b1[g * 8 + j]; }

    float dv = dinv[n];
    float dv2 = dv * dv;
    float sv0 = s[n * BATCH + b];
    float acc[8];
#pragma unroll
    for (int j = 0; j < 8; j++)
        acc[j] = dv2 * fmaxf(fmaf(sv0, w1r[j], b1r[j]), 0.0f);

    int beg = row_ptr[n], end = row_ptr[n + 1];
    for (int i = beg; i < end; i += 8) {
        float sv[8], wv[8];
#pragma unroll
        for (int u = 0; u < 8; u++) {
            int e = i + u;
            int c = (e < end) ? col[e] : n;     // col/val are block-uniform -> scalar loads
            wv[u] = (e < end) ? val[e] : 0.0f;
            sv[u] = s[c * BATCH + b];           // 8 independent gathers in flight
        }
#pragma unroll
        for (int u = 0; u < 8; u++)
#pragma unroll
            for (int j = 0; j < 8; j++)
                acc[j] = fmaf(wv[u], fmaxf(fmaf(sv[u], w1r[j], b1r[j]), 0.0f), acc[j]);
    }
#pragma unroll
    for (int j = 0; j < 8; j++) aggs[g * 8 + j][b] = acc[j];
    __syncthreads();

    // GEMM: out[b, f-slice g*8..+7] = relu(b2 + sum_k aggs[k][b] * w2s[k][f])
    float o[8];
#pragma unroll
    for (int j = 0; j < 8; j++) o[j] = b2[g * 8 + j];
#pragma unroll 8
    for (int k = 0; k < 64; k++) {
        float hv = aggs[k][b];
        float4 wa = *(const float4*)&w2s[k * 64 + g * 8];
        float4 wb = *(const float4*)&w2s[k * 64 + g * 8 + 4];
        o[0] = fmaf(hv, wa.x, o[0]); o[1] = fmaf(hv, wa.y, o[1]);
        o[2] = fmaf(hv, wa.z, o[2]); o[3] = fmaf(hv, wa.w, o[3]);
        o[4] = fmaf(hv, wb.x, o[4]); o[5] = fmaf(hv, wb.y, o[5]);
        o[6] = fmaf(hv, wb.z, o[6]); o[7] = fmaf(hv, wb.w, o[7]);
    }
    float4 r0, r1;
    r0.x = fmaxf(o[0], 0.f); r0.y = fmaxf(o[1], 0.f);
    r0.z = fmaxf(o[2], 0.f); r0.w = fmaxf(o[3], 0.f);
    r1.x = fmaxf(o[4], 0.f); r1.y = fmaxf(o[5], 0.f);
    r1.z = fmaxf(o[6], 0.f); r1.w = fmaxf(o[7], 0.f);
    float* op = out + 2 * BF + (size_t)b * (N_NODES * FDIM) + n * FDIM + g * 8;
    ((float4*)op)[0] = r0;
    ((float4*)op)[1] = r1;
}

// pooled[b,f] += partials; 1280 blocks = 32 b x 40 chunks of 125 rows
__global__ __launch_bounds__(256) void k_pooled(const float* __restrict__ out,
                                                float* __restrict__ pooled) {
    int bid = blockIdx.x;
    int b = bid / 40, chunk = bid % 40;
    int sub = threadIdx.x >> 6;
    int f = threadIdx.x & 63;
    const float* g = out + 2 * BF + (size_t)b * (N_NODES * FDIM) + (chunk * 125) * FDIM + f;
    int r0 = sub * 32;
    int r1 = r0 + 32; if (r1 > 125) r1 = 125;
    float acc = 0.f;
    for (int r = r0; r < r1; r++) acc += g[r * FDIM];
    atomicAdd(&pooled[b * FDIM + f], acc);
}

__global__ void k_head(const float* __restrict__ pooled, const float* __restrict__ Wmu,
                       const float* __restrict__ bmu, const float* __restrict__ Wlv,
                       const float* __restrict__ blv, float* __restrict__ out) {
    int id = blockIdx.x * 256 + threadIdx.x;
    if (id >= BF) return;
    int b = id >> 6, f = id & 63;
    const float sc = 1.0f / 5000.0f;
    float mu = bmu[f], lv = blv[f];
    for (int k = 0; k < 64; k++) {
        float p = pooled[b * 64 + k] * sc;
        mu = fmaf(p, Wmu[k * 64 + f], mu);
        lv = fmaf(p, Wlv[k * 64 + f], lv);
    }
    out[id] = mu;
    out[BF + id] = lv;
}

extern "C" void kernel_launch(void* const* d_in, const int* in_sizes, int n_in,
                              void* d_out, int out_size, void* d_ws, size_t ws_size,
                              hipStream_t stream) {
    const float* x   = (const float*)d_in[0];
    const int*   era = (const int*)d_in[1];
    const float* W1  = (const float*)d_in[2];
    const float* b1  = (const float*)d_in[3];
    const float* W2  = (const float*)d_in[4];
    const float* b2  = (const float*)d_in[5];
    const float* Wmu = (const float*)d_in[6];
    const float* bmu = (const float*)d_in[7];
    const float* Wlv = (const float*)d_in[8];
    const float* blv = (const float*)d_in[9];
    float* out = (float*)d_out;
    char*  ws  = (char*)d_ws;

    int*   deg    = (int*)(ws + OFF_DEG);
    int*   fill   = (int*)(ws + OFF_FILL);
    float* pooled = (float*)(ws + OFF_POOLED);
    float* dinv   = (float*)(ws + OFF_DINV);
    int*   rowp   = (int*)(ws + OFF_ROWPTR);
    int*   edges  = (int*)(ws + OFF_EDGES);
    int*   col    = (int*)(ws + OFF_COL);
    float* val    = (float*)(ws + OFF_VAL);
    float* xT     = (float*)(ws + OFF_XT);
    float* s      = (float*)(ws + OFF_S);

    hipMemsetAsync(ws, 0, ZERO_BYTES, stream);
    k_edges<<<625, 256, 0, stream>>>((const unsigned int*)era, edges, deg);
    k_transpose<<<625, 256, 0, stream>>>(x, xT);
    k_scan<<<1, 1024, 0, stream>>>(deg, rowp, dinv);
    k_fill<<<313, 256, 0, stream>>>(edges, rowp, fill, dinv, col, val);
    k_spmm1<<<625, 256, 0, stream>>>(xT, rowp, col, val, dinv, s);
    k_l2fused<<<5000, 256, 0, stream>>>(s, rowp, col, val, dinv, W1, b1, W2, b2, out);
    k_pooled<<<1280, 256, 0, stream>>>(out, pooled);
    k_head<<<8, 256, 0, stream>>>(pooled, Wmu, bmu, Wlv, blv, out);
}

// Round 7
// 158.809 us; speedup vs baseline: 2.1859x; 1.0962x over previous
//
#include <hip/hip_runtime.h>
#include <hip/hip_bf16.h>

#define N_NODES 5000
#define N_EDGES 80000
#define BATCH   32
#define FDIM    64
#define BF      (BATCH * FDIM)   // 2048
#define NSPREAD 64               // pooled contention spread

// ---- workspace layout (bytes) ----
#define OFF_DEG      0           // int[5000]
#define OFF_FILL     20480       // int[5000]
#define OFF_POOLEDP  40960       // float[NSPREAD*2048] = 512KB
#define ZERO_BYTES   565248
#define OFF_DINV     565248      // float[5000]
#define OFF_ROWPTR   585728      // int[5001]
#define OFF_EDGES    606208      // int[160000]
#define OFF_COL      1246208     // int[80000]
#define OFF_VAL      1566208     // float[80000]
#define OFF_XT       1886208     // float[5000*32]
#define OFF_S        2526208     // float[5000*32]
#define OFF_W2H      3166208     // short[4096]  W2 hi, TRANSPOSED [f][k]
#define OFF_W2L      3174400     // short[4096]  W2 lo, TRANSPOSED [f][k]

typedef __attribute__((ext_vector_type(8))) short short8;
typedef __attribute__((ext_vector_type(4))) float f32x4;

__device__ inline short f2bf(float f) {           // RTNE f32 -> bf16 bits
    unsigned u = __builtin_bit_cast(unsigned, f);
    unsigned r = (u + 0x7fffu + ((u >> 16) & 1u)) >> 16;
    return (short)r;
}
__device__ inline float bf2f(short h) {
    unsigned u = ((unsigned)(unsigned short)h) << 16;
    return __builtin_bit_cast(float, u);
}

// edge convert (int64|int32) + degree + x transpose + W2 bf16 hi/lo split (transposed)
__global__ void k_pre(const unsigned int* __restrict__ raw, const float* __restrict__ x,
                      const float* __restrict__ W2, int* __restrict__ edges,
                      int* __restrict__ deg, float* __restrict__ xT,
                      short* __restrict__ w2hT, short* __restrict__ w2lT) {
    unsigned int hi = raw[2 * (threadIdx.x & 63) + 1];
    bool is64 = (__ballot(hi == 0u) == ~0ull);
    int i = blockIdx.x * 256 + threadIdx.x;
    if (i < 2 * N_EDGES) {
        int v = is64 ? (int)raw[2 * i] : (int)raw[i];
        edges[i] = v;
        if (i >= N_EDGES) atomicAdd(&deg[v], 1);
    }
    if (i < BATCH * N_NODES) {   // 160000, same range
        int b = i / N_NODES, n = i % N_NODES;
        xT[n * BATCH + b] = x[i];
    }
    if (i < FDIM * FDIM) {
        float w = W2[i];
        int k = i >> 6, f = i & 63;
        short h = f2bf(w);
        w2hT[f * 64 + k] = h;
        w2lT[f * 64 + k] = f2bf(w - bf2f(h));
    }
}

// exclusive scan of deg[5000] -> row_ptr[5001], fused dinv = 1/sqrt(deg+1)
__global__ void k_scan(const int* __restrict__ deg, int* __restrict__ row_ptr,
                       float* __restrict__ dinv) {
    __shared__ int part[1024];
    int tid = threadIdx.x;
    int base = tid * 5;
    int local[5];
    int sum = 0;
    for (int i = 0; i < 5; i++) {
        int idx = base + i;
        int v = 0;
        if (idx < N_NODES) {
            v = deg[idx];
            dinv[idx] = 1.0f / sqrtf((float)v + 1.0f);
        }
        local[i] = sum;
        sum += v;
    }
    part[tid] = sum;
    __syncthreads();
    for (int off = 1; off < 1024; off <<= 1) {
        int v = (tid >= off) ? part[tid - off] : 0;
        __syncthreads();
        part[tid] += v;
        __syncthreads();
    }
    int prefix = (tid > 0) ? part[tid - 1] : 0;
    for (int i = 0; i < 5; i++) {
        int idx = base + i;
        if (idx < N_NODES) row_ptr[idx] = prefix + local[i];
    }
    if (tid == 1023) row_ptr[N_NODES] = part[1023];
}

__global__ void k_fill(const int* __restrict__ edges, const int* __restrict__ row_ptr,
                       int* __restrict__ fill, const float* __restrict__ dinv,
                       int* __restrict__ col, float* __restrict__ val) {
    int e = blockIdx.x * 256 + threadIdx.x;
    if (e >= N_EDGES) return;
    int s = edges[e];
    int d = edges[N_EDGES + e];
    int pos = atomicAdd(&fill[d], 1);
    int idx = row_ptr[d] + pos;
    col[idx] = s;
    val[idx] = dinv[s] * dinv[d];
}

// s = Â x : width-32 SpMM with 8-deep gather prefetch
__global__ __launch_bounds__(256) void k_spmm1(const float* __restrict__ xT,
                                               const int* __restrict__ row_ptr,
                                               const int* __restrict__ col,
                                               const float* __restrict__ val,
                                               const float* __restrict__ dinv,
                                               float* __restrict__ s_out) {
    int g = threadIdx.x >> 5;
    int lane = threadIdx.x & 31;
    int n = blockIdx.x * 8 + g;
    if (n >= N_NODES) return;
    float dv = dinv[n];
    float acc = dv * dv * xT[n * BATCH + lane];
    int beg = row_ptr[n], end = row_ptr[n + 1];
    for (int i = beg; i < end; i += 8) {
        float pv[8], wv[8];
#pragma unroll
        for (int u = 0; u < 8; u++) {
            int e = i + u;
            int c = (e < end) ? col[e] : n;
            wv[u] = (e < end) ? val[e] : 0.0f;
            pv[u] = xT[c * BATCH + lane];
        }
#pragma unroll
        for (int u = 0; u < 8; u++) acc = fmaf(wv[u], pv[u], acc);
    }
    s_out[n * BATCH + lane] = acc;
}

// Fused: layer-1 recompute + layer-2 aggregation (VALU) + per-node 32x64x64 GEMM
// on MFMA (bf16 hi/lo split, 3 mfma/tile) + bias + relu + transposed out-write
// + pooled accumulation via spread atomics.
__global__ __launch_bounds__(256) void k_l2fused(const float* __restrict__ s,
                                                 const int* __restrict__ row_ptr,
                                                 const int* __restrict__ col,
                                                 const float* __restrict__ val,
                                                 const float* __restrict__ dinv,
                                                 const float* __restrict__ W1,
                                                 const float* __restrict__ b1,
                                                 const short* __restrict__ w2hT,
                                                 const short* __restrict__ w2lT,
                                                 const float* __restrict__ b2,
                                                 float* __restrict__ out,
                                                 float* __restrict__ pooledP) {
    __shared__ float aggs[FDIM][BATCH];   // [k][b], 8 KB
    int n = blockIdx.x;
    int g = threadIdx.x >> 5, b = threadIdx.x & 31;

    float w1r[8], b1r[8];
#pragma unroll
    for (int j = 0; j < 8; j++) { w1r[j] = W1[g * 8 + j]; b1r[j] = b1[g * 8 + j]; }

    float dv = dinv[n];
    float dv2 = dv * dv;
    float sv0 = s[n * BATCH + b];
    float acc[8];
#pragma unroll
    for (int j = 0; j < 8; j++)
        acc[j] = dv2 * fmaxf(fmaf(sv0, w1r[j], b1r[j]), 0.0f);

    int beg = row_ptr[n], end = row_ptr[n + 1];
    for (int i = beg; i < end; i += 8) {
        float sv[8], wv[8];
#pragma unroll
        for (int u = 0; u < 8; u++) {
            int e = i + u;
            int c2 = (e < end) ? col[e] : n;    // block-uniform -> scalar loads
            wv[u] = (e < end) ? val[e] : 0.0f;
            sv[u] = s[c2 * BATCH + b];          // 8 gathers in flight
        }
#pragma unroll
        for (int u = 0; u < 8; u++)
#pragma unroll
            for (int j = 0; j < 8; j++)
                acc[j] = fmaf(wv[u], fmaxf(fmaf(sv[u], w1r[j], b1r[j]), 0.0f), acc[j]);
    }
#pragma unroll
    for (int j = 0; j < 8; j++) aggs[g * 8 + j][b] = acc[j];
    __syncthreads();

    // ---- MFMA GEMM: D[32b x 64f] = A[32b x 64k] * W2[64k x 64f] ----
    // wave -> (mt = wave>>1, nt half = wave&1); 1x2 D-tiles, K-tiles 2, 3-way split
    int lane = threadIdx.x & 63;
    int wave = threadIdx.x >> 6;
    int c = lane & 15, q = lane >> 4;
    int mt = wave >> 1;
    int nt0 = (wave & 1) * 2;

    short8 bh[2][2], bl[2][2];   // [nti][kt]
#pragma unroll
    for (int nti = 0; nti < 2; nti++)
#pragma unroll
        for (int kt = 0; kt < 2; kt++) {
            int f = (nt0 + nti) * 16 + c;
            bh[nti][kt] = *(const short8*)&w2hT[f * 64 + kt * 32 + q * 8];
            bl[nti][kt] = *(const short8*)&w2lT[f * 64 + kt * 32 + q * 8];
        }
    short8 ah[2], al[2];
    int brow = mt * 16 + c;      // A-frag row (b index)
#pragma unroll
    for (int kt = 0; kt < 2; kt++)
#pragma unroll
        for (int j = 0; j < 8; j++) {
            float a = aggs[kt * 32 + q * 8 + j][brow];
            short h = f2bf(a);
            ah[kt][j] = h;
            al[kt][j] = f2bf(a - bf2f(h));
        }
    f32x4 dacc[2];
#pragma unroll
    for (int nti = 0; nti < 2; nti++) dacc[nti] = (f32x4){0.f, 0.f, 0.f, 0.f};
#pragma unroll
    for (int nti = 0; nti < 2; nti++)
#pragma unroll
        for (int kt = 0; kt < 2; kt++) {
            dacc[nti] = __builtin_amdgcn_mfma_f32_16x16x32_bf16(al[kt], bh[nti][kt], dacc[nti], 0, 0, 0);
            dacc[nti] = __builtin_amdgcn_mfma_f32_16x16x32_bf16(ah[kt], bl[nti][kt], dacc[nti], 0, 0, 0);
            dacc[nti] = __builtin_amdgcn_mfma_f32_16x16x32_bf16(ah[kt], bh[nti][kt], dacc[nti], 0, 0, 0);
        }
    // epilogue: D row = q*4+r (b-local), col = c (f-local)
#pragma unroll
    for (int nti = 0; nti < 2; nti++) {
        int f = (nt0 + nti) * 16 + c;
        float bias = b2[f];
#pragma unroll
        for (int r = 0; r < 4; r++) {
            int bb = mt * 16 + q * 4 + r;
            float v = fmaxf(dacc[nti][r] + bias, 0.0f);
            out[2 * BF + (size_t)bb * (N_NODES * FDIM) + n * FDIM + f] = v;
            atomicAdd(&pooledP[(n & (NSPREAD - 1)) * BF + bb * 64 + f], v);
        }
    }
}

// reduce NSPREAD pooled copies + mean + both heads. 32 blocks (b) x 64 threads (f)
__global__ void k_head(const float* __restrict__ pooledP, const float* __restrict__ Wmu,
                       const float* __restrict__ bmu, const float* __restrict__ Wlv,
                       const float* __restrict__ blv, float* __restrict__ out) {
    __shared__ float pb[64];
    int b = blockIdx.x, f = threadIdx.x;
    float acc = 0.f;
    for (int c = 0; c < NSPREAD; c++) acc += pooledP[c * BF + b * 64 + f];
    pb[f] = acc * (1.0f / 5000.0f);
    __syncthreads();
    float mu = bmu[f], lv = blv[f];
#pragma unroll 8
    for (int k = 0; k < 64; k++) {
        float p = pb[k];
        mu = fmaf(p, Wmu[k * 64 + f], mu);
        lv = fmaf(p, Wlv[k * 64 + f], lv);
    }
    out[b * 64 + f] = mu;
    out[BF + b * 64 + f] = lv;
}

extern "C" void kernel_launch(void* const* d_in, const int* in_sizes, int n_in,
                              void* d_out, int out_size, void* d_ws, size_t ws_size,
                              hipStream_t stream) {
    const float* x   = (const float*)d_in[0];
    const int*   era = (const int*)d_in[1];
    const float* W1  = (const float*)d_in[2];
    const float* b1  = (const float*)d_in[3];
    const float* W2  = (const float*)d_in[4];
    const float* b2  = (const float*)d_in[5];
    const float* Wmu = (const float*)d_in[6];
    const float* bmu = (const float*)d_in[7];
    const float* Wlv = (const float*)d_in[8];
    const float* blv = (const float*)d_in[9];
    float* out = (float*)d_out;
    char*  ws  = (char*)d_ws;

    int*   deg     = (int*)(ws + OFF_DEG);
    int*   fill    = (int*)(ws + OFF_FILL);
    float* pooledP = (float*)(ws + OFF_POOLEDP);
    float* dinv    = (float*)(ws + OFF_DINV);
    int*   rowp    = (int*)(ws + OFF_ROWPTR);
    int*   edges   = (int*)(ws + OFF_EDGES);
    int*   col     = (int*)(ws + OFF_COL);
    float* val     = (float*)(ws + OFF_VAL);
    float* xT      = (float*)(ws + OFF_XT);
    float* s       = (float*)(ws + OFF_S);
    short* w2hT    = (short*)(ws + OFF_W2H);
    short* w2lT    = (short*)(ws + OFF_W2L);

    hipMemsetAsync(ws, 0, ZERO_BYTES, stream);
    k_pre<<<625, 256, 0, stream>>>((const unsigned int*)era, x, W2, edges, deg, xT, w2hT, w2lT);
    k_scan<<<1, 1024, 0, stream>>>(deg, rowp, dinv);
    k_fill<<<313, 256, 0, stream>>>(edges, rowp, fill, dinv, col, val);
    k_spmm1<<<625, 256, 0, stream>>>(xT, rowp, col, val, dinv, s);
    k_l2fused<<<5000, 256, 0, stream>>>(s, rowp, col, val, dinv, W1, b1, w2hT, w2lT, b2, out, pooledP);
    k_head<<<32, 64, 0, stream>>>(pooledP, Wmu, bmu, Wlv, blv, out);
}